// Round 1
// 550.723 us; speedup vs baseline: 1.0593x; 1.0593x over previous
//
#include <hip/hip_runtime.h>

// Problem constants (B=4,H=16,N=8192,D=E=64, fp32 in/out)
constexpr int BH   = 64;      // B*H
constexpr int NN   = 8192;
constexpr int DD   = 64;
constexpr int EE   = 64;
constexpr int ST   = 72;      // LDS stride in bf16 elems: 144 B, 16B-aligned, breaks pow2 banks
constexpr int NSPLIT_KV  = 16;            // kv-role blocks per (b,h)
constexpr int NSPLIT_OUT = 32;            // out-role blocks per (b,h)
constexpr int ROWS_KV  = NN / NSPLIT_KV;  // 512
constexpr int ROWS_OUT = NN / NSPLIT_OUT; // 256
constexpr int CHUNK = 64;                 // rows per inner iteration
constexpr int NCH_KV  = ROWS_KV / CHUNK;  // 8
constexpr int NCH_OUT = ROWS_OUT / CHUNK; // 4
constexpr float EPS_ = 1e-10f;

typedef __attribute__((ext_vector_type(8))) short short8;   // 8 bf16 = 4 VGPRs (A/B frag)
typedef __attribute__((ext_vector_type(4))) float f32x4;    // C/D frag

#define MFMA16(a, b, c) __builtin_amdgcn_mfma_f32_16x16x32_bf16((a), (b), (c), 0, 0, 0)

__device__ __forceinline__ unsigned short f2bf(float f) {
  union { float f; unsigned u; } v; v.f = f;
  unsigned r = v.u + 0x7fffu + ((v.u >> 16) & 1u);   // round-to-nearest-even
  return (unsigned short)(r >> 16);
}
__device__ __forceinline__ float bf2f(unsigned short s) {
  union { unsigned u; float f; } v; v.u = ((unsigned)s) << 16;
  return v.f;
}
__device__ __forceinline__ float elu1(float x) {     // elu(x)+1
  return x > 0.0f ? x + 1.0f : __expf(x);
}

// ---------------------------------------------------------------------------
// Kernel 0: initialize new_kv/new_norm output regions with past values
// (d_out is re-poisoned before every launch; kv-role atomically adds)
// ---------------------------------------------------------------------------
__global__ void fw_init_kernel(const float* __restrict__ past_kv,
                               const float* __restrict__ past_norm,
                               float* __restrict__ out_kv,
                               float* __restrict__ out_norm) {
  int i = blockIdx.x * 256 + threadIdx.x;
  if (i < BH * DD * EE) out_kv[i] = past_kv[i];
  if (i < BH * DD)      out_norm[i] = past_norm[i];
}

// ---------------------------------------------------------------------------
// Fused main kernel. Role by blockIdx.x % 3:
//   rem==0  (1024 blocks): kv-side  — k=elu(keys)+1; delta_v=(k@pkv)/(k·pnorm);
//                          new_kv += k^T(values-delta_v); new_norm += sum k
//   rem!=0  (2048 blocks): out-side — q=elu(queries)+1; mem=(q@pkv)/(q·pnorm);
//                          out_g = out*g + mem*(1-g)
// Both roles are latency-bound streams; interleaving them on every CU plus a
// one-chunk register prefetch pipeline hides HBM latency.
// LDS = 37.6 KB -> 4 blocks/CU (16 waves). VGPR target <=128 (launch_bounds 4).
// ---------------------------------------------------------------------------
__global__ __launch_bounds__(256, 4) void fw_main_kernel(
    const float* __restrict__ keys, const float* __restrict__ values,
    const float* __restrict__ queries, const float* __restrict__ outin,
    const float* __restrict__ past_kv, const float* __restrict__ past_norm,
    const float* __restrict__ head_gates, float* __restrict__ out_g,
    float* __restrict__ out_kv, float* __restrict__ out_norm) {
  __shared__ unsigned short pkvT[EE * ST];   // past_kv^T bf16 [e][d]   (GEMM A)
  __shared__ unsigned short bufN[CHUNK * ST];// k/q bf16 [n][d]         (GEMM B)
  __shared__ unsigned short kT  [DD * ST];   // k^T bf16 [d][n]         (kv GEMM2 B)
  __shared__ unsigned short bufE[EE * ST];   // v^T [e][n] (kv) / mem [n][e] (out)
  __shared__ float pnorm_s[DD];
  __shared__ float denom_s[CHUNK];
  __shared__ float norm_part[DD];

  const int t   = threadIdx.x;
  const int bid = blockIdx.x;
  const int rem = bid % 3;                   // 0 -> kv role, 1/2 -> out role
  const int sub = bid / 3;

  int bh, row0;
  if (rem == 0) {
    bh = sub & (BH - 1); row0 = (sub >> 6) * ROWS_KV;
  } else {
    int oidx = sub * 2 + rem - 1;            // 0..2047
    bh = oidx & (BH - 1); row0 = (oidx >> 6) * ROWS_OUT;
  }

  if (t < DD) { pnorm_s[t] = past_norm[bh * DD + t]; norm_part[t] = 0.0f; }
  // stage past_kv -> pkvT (bf16, transposed). Once per block.
  #pragma unroll
  for (int p = 0; p < 4; ++p) {
    int idx = p * 1024 + t * 4;
    int d = idx >> 6, e0 = idx & 63;
    f32x4 v4 = *(const f32x4*)&past_kv[(long)bh * DD * EE + idx];
    pkvT[(e0 + 0) * ST + d] = f2bf(v4[0]);
    pkvT[(e0 + 1) * ST + d] = f2bf(v4[1]);
    pkvT[(e0 + 2) * ST + d] = f2bf(v4[2]);
    pkvT[(e0 + 3) * ST + d] = f2bf(v4[3]);
  }
  __syncthreads();

  const int l = t & 63, w = t >> 6;          // wave id 0..3
  const int l16 = l & 15, q = l >> 4;        // MFMA lane decomposition
  const int d0 = (t & 15) * 4;               // staging column
  const int r0 = t >> 4;                     // staging row within 16-group
  const int nb = w * 16;                     // wave's n-tile
  const long gbase = (long)bh * NN * DD;

  if (rem == 0) {
    // ================= kv role =================
    f32x4 kreg[4], vreg[4];
    #pragma unroll
    for (int p = 0; p < 4; ++p) {
      kreg[p] = *(const f32x4*)&keys[gbase + (long)(row0 + p * 16 + r0) * DD + d0];
      // values loaded directly in GEMM1-C consumer layout: row nb+l16, col p*16+q*4
      vreg[p] = *(const f32x4*)&values[gbase + (long)(row0 + nb + l16) * EE + p * 16 + q * 4];
    }
    float na0 = 0.f, na1 = 0.f, na2 = 0.f, na3 = 0.f;
    f32x4 acc2[4];
    #pragma unroll
    for (int i = 0; i < 4; ++i) acc2[i] = (f32x4){0.f, 0.f, 0.f, 0.f};

    for (int c = 0; c < NCH_KV; ++c) {
      // ---- phase 1: k -> LDS (both layouts) + fp32 denom ----
      #pragma unroll
      for (int p = 0; p < 4; ++p) {
        const int nl = p * 16 + r0;
        float k0 = elu1(kreg[p][0]), k1 = elu1(kreg[p][1]);
        float k2 = elu1(kreg[p][2]), k3 = elu1(kreg[p][3]);
        ushort4 kb; kb.x = f2bf(k0); kb.y = f2bf(k1); kb.z = f2bf(k2); kb.w = f2bf(k3);
        *(ushort4*)&bufN[nl * ST + d0] = kb;
        kT[(d0 + 0) * ST + nl] = kb.x;
        kT[(d0 + 1) * ST + nl] = kb.y;
        kT[(d0 + 2) * ST + nl] = kb.z;
        kT[(d0 + 3) * ST + nl] = kb.w;
        float part = k0 * pnorm_s[d0] + k1 * pnorm_s[d0 + 1]
                   + k2 * pnorm_s[d0 + 2] + k3 * pnorm_s[d0 + 3];
        part += __shfl_xor(part, 1);
        part += __shfl_xor(part, 2);
        part += __shfl_xor(part, 4);
        part += __shfl_xor(part, 8);
        if (l16 == 0) denom_s[nl] = part;
        na0 += k0; na1 += k1; na2 += k2; na3 += k3;
      }
      // ---- prefetch chunk c+1 (consumed next iteration; hidden under GEMMs) ----
      const bool more = (c + 1 < NCH_KV);
      f32x4 kregN[4], vregN[4];
      if (more) {
        const int rown = row0 + (c + 1) * CHUNK;
        #pragma unroll
        for (int p = 0; p < 4; ++p) {
          kregN[p] = *(const f32x4*)&keys[gbase + (long)(rown + p * 16 + r0) * DD + d0];
          vregN[p] = *(const f32x4*)&values[gbase + (long)(rown + nb + l16) * EE + p * 16 + q * 4];
        }
      }
      __syncthreads();

      // ---- GEMM1 (transposed): D[e][n] = sum_d pkvT[e][d]*k[n][d]; wave -> n-tile nb ----
      f32x4 acc1[4];
      #pragma unroll
      for (int i = 0; i < 4; ++i) acc1[i] = (f32x4){0.f, 0.f, 0.f, 0.f};
      #pragma unroll
      for (int s = 0; s < 2; ++s) {
        short8 bfrag = *(const short8*)&bufN[(nb + l16) * ST + s * 32 + q * 8];
        #pragma unroll
        for (int et = 0; et < 4; ++et) {
          short8 afrag = *(const short8*)&pkvT[(et * 16 + l16) * ST + s * 32 + q * 8];
          acc1[et] = MFMA16(afrag, bfrag, acc1[et]);
        }
      }
      // v = values - numer/denom (values fp32 from regs), write v^T for GEMM2 A
      const float rd = 1.0f / fmaxf(denom_s[nb + l16], EPS_);
      #pragma unroll
      for (int et = 0; et < 4; ++et) {
        #pragma unroll
        for (int i = 0; i < 4; ++i) {
          const int e = et * 16 + q * 4 + i;   // C-layout: row=e, col=n=nb+l16
          bufE[e * ST + nb + l16] = f2bf(vreg[et][i] - acc1[et][i] * rd);
        }
      }
      __syncthreads();

      // ---- GEMM2: new_kv^T[e][d] += sum_n vT[e][n]*kT[d][n]; wave = e-tile w ----
      #pragma unroll
      for (int s = 0; s < 2; ++s) {
        short8 afrag = *(const short8*)&bufE[(nb + l16) * ST + s * 32 + q * 8];
        #pragma unroll
        for (int dt = 0; dt < 4; ++dt) {
          short8 bfrag = *(const short8*)&kT[(dt * 16 + l16) * ST + s * 32 + q * 8];
          acc2[dt] = MFMA16(afrag, bfrag, acc2[dt]);
        }
      }
      __syncthreads();   // protect bufN/kT/bufE before next chunk's phase 1

      if (more) {
        #pragma unroll
        for (int p = 0; p < 4; ++p) { kreg[p] = kregN[p]; vreg[p] = vregN[p]; }
      }
    }

    // ---- epilogue: norm reduce + atomic adds ----
    atomicAdd(&norm_part[d0 + 0], na0);
    atomicAdd(&norm_part[d0 + 1], na1);
    atomicAdd(&norm_part[d0 + 2], na2);
    atomicAdd(&norm_part[d0 + 3], na3);
    __syncthreads();
    if (t < DD) atomicAdd(&out_norm[bh * DD + t], norm_part[t]);
    #pragma unroll
    for (int dt = 0; dt < 4; ++dt) {
      #pragma unroll
      for (int i = 0; i < 4; ++i) {
        const int d = dt * 16 + l16;
        const int e = nb + q * 4 + i;
        atomicAdd(&out_kv[(long)bh * DD * EE + d * EE + e], acc2[dt][i]);
      }
    }
  } else {
    // ================= out role =================
    const float hg = head_gates[bh & 15];    // bh = b*H + h -> h = bh%16
    const float g = 1.0f / (1.0f + __expf(-hg));
    const float gm1 = 1.0f - g;

    f32x4 qreg[4], oreg[4];
    #pragma unroll
    for (int p = 0; p < 4; ++p) {
      qreg[p] = *(const f32x4*)&queries[gbase + (long)(row0 + p * 16 + r0) * DD + d0];
      oreg[p] = *(const f32x4*)&outin[gbase + (long)(row0 + p * 16 + r0) * EE + d0];
    }

    for (int c = 0; c < NCH_OUT; ++c) {
      const int rowc = row0 + c * CHUNK;
      // ---- phase 1: q -> LDS + fp32 denom ----
      #pragma unroll
      for (int p = 0; p < 4; ++p) {
        const int nl = p * 16 + r0;
        float q0 = elu1(qreg[p][0]), q1 = elu1(qreg[p][1]);
        float q2 = elu1(qreg[p][2]), q3 = elu1(qreg[p][3]);
        ushort4 qb; qb.x = f2bf(q0); qb.y = f2bf(q1); qb.z = f2bf(q2); qb.w = f2bf(q3);
        *(ushort4*)&bufN[nl * ST + d0] = qb;
        float part = q0 * pnorm_s[d0] + q1 * pnorm_s[d0 + 1]
                   + q2 * pnorm_s[d0 + 2] + q3 * pnorm_s[d0 + 3];
        part += __shfl_xor(part, 1);
        part += __shfl_xor(part, 2);
        part += __shfl_xor(part, 4);
        part += __shfl_xor(part, 8);
        if (l16 == 0) denom_s[nl] = part;
      }
      // ---- prefetch chunk c+1 ----
      const bool more = (c + 1 < NCH_OUT);
      f32x4 qregN[4], oregN[4];
      if (more) {
        const int rown = rowc + CHUNK;
        #pragma unroll
        for (int p = 0; p < 4; ++p) {
          qregN[p] = *(const f32x4*)&queries[gbase + (long)(rown + p * 16 + r0) * DD + d0];
          oregN[p] = *(const f32x4*)&outin[gbase + (long)(rown + p * 16 + r0) * EE + d0];
        }
      }
      __syncthreads();

      // ---- GEMM (transposed): D[e][n] = sum_d pkvT[e][d]*q[n][d] ----
      f32x4 acc[4];
      #pragma unroll
      for (int i = 0; i < 4; ++i) acc[i] = (f32x4){0.f, 0.f, 0.f, 0.f};
      #pragma unroll
      for (int s = 0; s < 2; ++s) {
        short8 bfrag = *(const short8*)&bufN[(nb + l16) * ST + s * 32 + q * 8];
        #pragma unroll
        for (int et = 0; et < 4; ++et) {
          short8 afrag = *(const short8*)&pkvT[(et * 16 + l16) * ST + s * 32 + q * 8];
          acc[et] = MFMA16(afrag, bfrag, acc[et]);
        }
      }
      const float rd = 1.0f / fmaxf(denom_s[nb + l16], EPS_);
      #pragma unroll
      for (int et = 0; et < 4; ++et) {
        #pragma unroll
        for (int i = 0; i < 4; ++i) {
          const int e = et * 16 + q * 4 + i;
          bufE[(nb + l16) * ST + e] = f2bf(acc[et][i] * rd);   // mem [n][e]
        }
      }
      __syncthreads();

      // ---- blend with prefetched `out` regs, coalesced store ----
      #pragma unroll
      for (int p = 0; p < 4; ++p) {
        const int nl = p * 16 + r0;
        ushort4 mb = *(const ushort4*)&bufE[nl * ST + d0];
        f32x4 o = oreg[p];
        f32x4 r;
        r[0] = o[0] * g + bf2f(mb.x) * gm1;
        r[1] = o[1] * g + bf2f(mb.y) * gm1;
        r[2] = o[2] * g + bf2f(mb.z) * gm1;
        r[3] = o[3] * g + bf2f(mb.w) * gm1;
        *(f32x4*)&out_g[gbase + (long)(rowc + nl) * EE + d0] = r;
      }
      if (more) {
        #pragma unroll
        for (int p = 0; p < 4; ++p) { qreg[p] = qregN[p]; oreg[p] = oregN[p]; }
      }
      // no extra sync needed: bufE next written only after the post-phase1 sync
    }
  }
}

extern "C" void kernel_launch(void* const* d_in, const int* in_sizes, int n_in,
                              void* d_out, int out_size, void* d_ws, size_t ws_size,
                              hipStream_t stream) {
  const float* keys      = (const float*)d_in[0];
  const float* values    = (const float*)d_in[1];
  const float* queries   = (const float*)d_in[2];
  const float* outin     = (const float*)d_in[3];
  const float* past_kv   = (const float*)d_in[4];
  const float* past_norm = (const float*)d_in[5];
  const float* head_gates= (const float*)d_in[6];

  float* out_g    = (float*)d_out;                       // [4,16,8192,64]
  float* out_kv   = out_g + (long)BH * NN * EE;          // [4,16,64,64]
  float* out_norm = out_kv + (long)BH * DD * EE;         // [4,16,64]

  fw_init_kernel<<<(BH * DD * EE + 255) / 256, 256, 0, stream>>>(
      past_kv, past_norm, out_kv, out_norm);
  // 1024 kv-role + 2048 out-role blocks, interleaved by bid%3
  fw_main_kernel<<<3 * BH * NSPLIT_KV, 256, 0, stream>>>(
      keys, values, queries, outin, past_kv, past_norm, head_gates,
      out_g, out_kv, out_norm);
}